// Round 1
// baseline (580.467 us; speedup 1.0000x reference)
//
#include <hip/hip_runtime.h>
#include <stdint.h>

#define DM 1024
#define NH 16
#define DKH 64
#define BB 4
#define SS 4096
#define MM (BB*SS)   // 16384

typedef __bf16 bf16x8 __attribute__((ext_vector_type(8)));
typedef float f32x4 __attribute__((ext_vector_type(4)));

__device__ __forceinline__ float bf2f(ushort u) {
  union { uint32_t i; float f; } v; v.i = ((uint32_t)u) << 16; return v.f;
}
__device__ __forceinline__ ushort f2bf(float f) {
  union { float f; uint32_t i; } v; v.f = f;
  uint32_t x = v.i;
  uint32_t r = (x + 0x7fffu + ((x >> 16) & 1u)) >> 16;
  return (ushort)r;
}
__device__ __forceinline__ void unpack8(uint4 u, float* o) {
  o[0] = bf2f((ushort)(u.x & 0xffff)); o[1] = bf2f((ushort)(u.x >> 16));
  o[2] = bf2f((ushort)(u.y & 0xffff)); o[3] = bf2f((ushort)(u.y >> 16));
  o[4] = bf2f((ushort)(u.z & 0xffff)); o[5] = bf2f((ushort)(u.z >> 16));
  o[6] = bf2f((ushort)(u.w & 0xffff)); o[7] = bf2f((ushort)(u.w >> 16));
}

#define GLL16(g, l) __builtin_amdgcn_global_load_lds( \
    (__attribute__((address_space(1))) void*)(g), \
    (__attribute__((address_space(3))) void*)(l), 16, 0, 0)

// ---------------- cast fp32 -> bf16 ----------------
__global__ void cast_kernel(const float* __restrict__ src, ushort* __restrict__ dst, int n) {
  int idx = blockIdx.x * blockDim.x + threadIdx.x;
  int stride = gridDim.x * blockDim.x;
  for (int i = idx * 4; i < n; i += stride * 4) {
    float4 v = *reinterpret_cast<const float4*>(src + i);
    ushort4 o;
    o.x = f2bf(v.x); o.y = f2bf(v.y); o.z = f2bf(v.z); o.w = f2bf(v.w);
    *reinterpret_cast<ushort4*>(dst + i) = o;
  }
}

// ---------------- bf16 GEMM: C[m,n] = sum_k A[m,k]*Bw[n,k] + bias[n] ----------------
// MODE 0: bf16 out, elu+1 ; MODE 1: bf16 out ; MODE 2: f32 out
template<int MODE>
__global__ __launch_bounds__(256) void gemm_bt(
    const ushort* __restrict__ A, const ushort* __restrict__ Bw,
    const float* __restrict__ bias, void* __restrict__ Cout,
    const int K, const int N) {
  __shared__ ushort Al[128 * 32];
  __shared__ ushort Bl[128 * 32];
  const int t = threadIdx.x;
  const int lane = t & 63;
  const int w = t >> 6;
  const int m0 = blockIdx.y * 128;
  const int n0 = blockIdx.x * 128;
  const int wm = (w >> 1) * 64;
  const int wn = (w & 1) * 64;
  f32x4 acc[4][4] = {};

  const int rowA = t >> 2;
  const int kc = (t & 3) * 8;
  const size_t baseA = (size_t)(m0 + rowA) * K + kc;
  const size_t baseB = (size_t)(n0 + rowA) * K + kc;
  ushort* lA = Al + w * 512;   // wave-uniform LDS base (+lane*16B done by HW)
  ushort* lB = Bl + w * 512;

  const int fr = lane & 15;
  const int kq = (lane >> 4) * 8;
  const ushort* ra = Al + (wm + fr) * 32 + kq;
  const ushort* rb = Bl + (wn + fr) * 32 + kq;

  for (int k0 = 0; k0 < K; k0 += 32) {
    __syncthreads();
    GLL16(A + baseA + k0, lA);
    GLL16(A + baseA + (size_t)64 * K + k0, lA + 2048);
    GLL16(Bw + baseB + k0, lB);
    GLL16(Bw + baseB + (size_t)64 * K + k0, lB + 2048);
    __syncthreads();
    bf16x8 a[4], b[4];
#pragma unroll
    for (int i = 0; i < 4; ++i) {
      a[i] = *reinterpret_cast<const bf16x8*>(ra + i * 16 * 32);
      b[i] = *reinterpret_cast<const bf16x8*>(rb + i * 16 * 32);
    }
#pragma unroll
    for (int mi = 0; mi < 4; ++mi)
#pragma unroll
      for (int ni = 0; ni < 4; ++ni)
        acc[mi][ni] = __builtin_amdgcn_mfma_f32_16x16x32_bf16(a[mi], b[ni], acc[mi][ni], 0, 0, 0);
  }

  const int fq = (lane >> 4) * 4;
#pragma unroll
  for (int mi = 0; mi < 4; ++mi) {
#pragma unroll
    for (int ni = 0; ni < 4; ++ni) {
      const int c = n0 + wn + ni * 16 + fr;
      const float bv = bias[c];
#pragma unroll
      for (int q = 0; q < 4; ++q) {
        const int r = m0 + wm + mi * 16 + fq + q;
        float v = acc[mi][ni][q] + bv;
        if constexpr (MODE == 0) v = (v > 0.f) ? (v + 1.f) : __expf(v);
        if constexpr (MODE == 2) {
          reinterpret_cast<float*>(Cout)[(size_t)r * N + c] = v;
        } else {
          reinterpret_cast<ushort*>(Cout)[(size_t)r * N + c] = f2bf(v);
        }
      }
    }
  }
}

// ---------------- KV[d][e] = sum_s K[s,d]*V[s,e] ; Ksum[d] = sum_s K[s,d] ----------------
__global__ __launch_bounds__(256) void kv_kernel(
    const ushort* __restrict__ Kp, const ushort* __restrict__ Vp,
    float* __restrict__ KV, float* __restrict__ Ksum) {
  const int bh = blockIdx.x;      // 64 = B*H
  const int chunk = blockIdx.y;   // 8 chunks of 512 rows
  const int b = bh >> 4, h = bh & 15;
  __shared__ float Kf[32][64];
  __shared__ float Vf[32][64];
  const int t = threadIdx.x;
  const int d = t >> 2, eb = (t & 3) * 16;
  float acc[16] = {};
  float ks = 0.f;
  const int r = t >> 3, c8 = (t & 7) * 8;
  const size_t gbase = (size_t)(b * SS + chunk * 512 + r) * DM + h * 64 + c8;
  for (int s0 = 0; s0 < 512; s0 += 32) {
    __syncthreads();
    uint4 uk = *reinterpret_cast<const uint4*>(Kp + gbase + (size_t)s0 * DM);
    uint4 uv = *reinterpret_cast<const uint4*>(Vp + gbase + (size_t)s0 * DM);
    unpack8(uk, &Kf[r][c8]);
    unpack8(uv, &Vf[r][c8]);
    __syncthreads();
#pragma unroll 4
    for (int s = 0; s < 32; ++s) {
      const float kd = Kf[s][d];
      ks += kd;
      const float* vr = &Vf[s][eb];
      const float4 v0 = *reinterpret_cast<const float4*>(vr);
      const float4 v1 = *reinterpret_cast<const float4*>(vr + 4);
      const float4 v2 = *reinterpret_cast<const float4*>(vr + 8);
      const float4 v3 = *reinterpret_cast<const float4*>(vr + 12);
      acc[0]  += kd * v0.x; acc[1]  += kd * v0.y; acc[2]  += kd * v0.z; acc[3]  += kd * v0.w;
      acc[4]  += kd * v1.x; acc[5]  += kd * v1.y; acc[6]  += kd * v1.z; acc[7]  += kd * v1.w;
      acc[8]  += kd * v2.x; acc[9]  += kd * v2.y; acc[10] += kd * v2.z; acc[11] += kd * v2.w;
      acc[12] += kd * v3.x; acc[13] += kd * v3.y; acc[14] += kd * v3.z; acc[15] += kd * v3.w;
    }
  }
  float* kvp = KV + (size_t)bh * 4096 + d * 64 + eb;
#pragma unroll
  for (int j = 0; j < 16; ++j) atomicAdd(kvp + j, acc[j]);
  if ((t & 3) == 0) atomicAdd(Ksum + bh * 64 + d, ks);
}

// ---------------- Z[s,e] = (sum_d Q[s,d]*KV[d,e]) / (sum_d Q[s,d]*Ksum[d] + 1e-6) ----------------
__global__ __launch_bounds__(256) void z_kernel(
    const ushort* __restrict__ Qp, const float* __restrict__ KV,
    const float* __restrict__ Ksum, ushort* __restrict__ Zn) {
  const int bh = blockIdx.y;
  const int b = bh >> 4, h = bh & 15;
  const int srow = blockIdx.x * 256 + threadIdx.x;
  const size_t g = (size_t)(b * SS + srow) * DM + h * 64;
  const float* __restrict__ kv = KV + (size_t)bh * 4096;
  const float* __restrict__ ksm = Ksum + bh * 64;
  float accz[64] = {};
  float accd = 0.f;
  for (int dc = 0; dc < 8; ++dc) {
    uint4 u = *reinterpret_cast<const uint4*>(Qp + g + dc * 8);
    float q[8];
    unpack8(u, q);
#pragma unroll
    for (int i = 0; i < 8; ++i) {
      const int dd = dc * 8 + i;
      accd += q[i] * ksm[dd];
      const float* row = kv + dd * 64;
#pragma unroll
      for (int e = 0; e < 64; ++e) accz[e] += q[i] * row[e];
    }
  }
  const float inv = 1.f / (accd + 1e-6f);
  ushort* o = Zn + g;
#pragma unroll
  for (int ec = 0; ec < 8; ++ec) {
    uint4 u;
    u.x = (uint32_t)f2bf(accz[ec*8+0]*inv) | ((uint32_t)f2bf(accz[ec*8+1]*inv) << 16);
    u.y = (uint32_t)f2bf(accz[ec*8+2]*inv) | ((uint32_t)f2bf(accz[ec*8+3]*inv) << 16);
    u.z = (uint32_t)f2bf(accz[ec*8+4]*inv) | ((uint32_t)f2bf(accz[ec*8+5]*inv) << 16);
    u.w = (uint32_t)f2bf(accz[ec*8+6]*inv) | ((uint32_t)f2bf(accz[ec*8+7]*inv) << 16);
    *reinterpret_cast<uint4*>(o + ec * 8) = u;
  }
}

extern "C" void kernel_launch(void* const* d_in, const int* in_sizes, int n_in,
                              void* d_out, int out_size, void* d_ws, size_t ws_size,
                              hipStream_t stream) {
  const float* query = (const float*)d_in[0];
  const float* key_  = (const float*)d_in[1];
  const float* value = (const float*)d_in[2];
  const float* w_q = (const float*)d_in[3];
  const float* b_q = (const float*)d_in[4];
  const float* w_k = (const float*)d_in[5];
  const float* b_k = (const float*)d_in[6];
  const float* w_v = (const float*)d_in[7];
  const float* b_v = (const float*)d_in[8];
  const float* w_o = (const float*)d_in[9];
  const float* b_o = (const float*)d_in[10];

  char* ws = (char*)d_ws;
  const size_t NX = (size_t)MM * DM;            // 16,777,216
  ushort* Xq = (ushort*)ws; ws += NX * 2;
  ushort* Xk = (ushort*)ws; ws += NX * 2;
  ushort* Xv = (ushort*)ws; ws += NX * 2;
  ushort* Wq = (ushort*)ws; ws += (size_t)DM * DM * 2;
  ushort* Wk = (ushort*)ws; ws += (size_t)DM * DM * 2;
  ushort* Wv = (ushort*)ws; ws += (size_t)DM * DM * 2;
  ushort* Wo = (ushort*)ws; ws += (size_t)DM * DM * 2;
  ushort* Qp = (ushort*)ws; ws += NX * 2;
  ushort* Kp = (ushort*)ws; ws += NX * 2;
  ushort* Vp = (ushort*)ws; ws += NX * 2;
  float*  KV = (float*)ws;  ws += (size_t)64 * 4096 * 4;
  float*  Ks = (float*)ws;  ws += (size_t)64 * 64 * 4;
  ushort* Zn = (ushort*)ws; ws += NX * 2;

  cast_kernel<<<2048, 256, 0, stream>>>(query, Xq, (int)NX);
  cast_kernel<<<2048, 256, 0, stream>>>(key_,  Xk, (int)NX);
  cast_kernel<<<2048, 256, 0, stream>>>(value, Xv, (int)NX);
  cast_kernel<<<256, 256, 0, stream>>>(w_q, Wq, DM * DM);
  cast_kernel<<<256, 256, 0, stream>>>(w_k, Wk, DM * DM);
  cast_kernel<<<256, 256, 0, stream>>>(w_v, Wv, DM * DM);
  cast_kernel<<<256, 256, 0, stream>>>(w_o, Wo, DM * DM);

  dim3 gg(DM / 128, MM / 128);   // (8, 128)
  gemm_bt<0><<<gg, 256, 0, stream>>>(Xq, Wq, b_q, Qp, DM, DM);
  gemm_bt<0><<<gg, 256, 0, stream>>>(Xk, Wk, b_k, Kp, DM, DM);
  gemm_bt<1><<<gg, 256, 0, stream>>>(Xv, Wv, b_v, Vp, DM, DM);

  hipMemsetAsync(KV, 0, ((size_t)64 * 4096 + 64 * 64) * sizeof(float), stream);
  kv_kernel<<<dim3(64, 8), 256, 0, stream>>>(Kp, Vp, KV, Ks);
  z_kernel<<<dim3(16, 64), 256, 0, stream>>>(Qp, KV, Ks, Zn);

  gemm_bt<2><<<gg, 256, 0, stream>>>(Zn, Wo, b_o, d_out, DM, DM);
}

// Round 3
// 449.805 us; speedup vs baseline: 1.2905x; 1.2905x over previous
//
#include <hip/hip_runtime.h>
#include <stdint.h>

#define DM 1024
#define NH 16
#define DKH 64
#define BB 4
#define SS 4096
#define MM (BB*SS)   // 16384

typedef __bf16 bf16x8 __attribute__((ext_vector_type(8)));
typedef float f32x4 __attribute__((ext_vector_type(4)));

__device__ __forceinline__ float bf2f(ushort u) {
  union { uint32_t i; float f; } v; v.i = ((uint32_t)u) << 16; return v.f;
}
__device__ __forceinline__ ushort f2bf(float f) {
  union { float f; uint32_t i; } v; v.f = f;
  uint32_t x = v.i;
  uint32_t r = (x + 0x7fffu + ((x >> 16) & 1u)) >> 16;
  return (ushort)r;
}
__device__ __forceinline__ void unpack8(uint4 u, float* o) {
  o[0] = bf2f((ushort)(u.x & 0xffff)); o[1] = bf2f((ushort)(u.x >> 16));
  o[2] = bf2f((ushort)(u.y & 0xffff)); o[3] = bf2f((ushort)(u.y >> 16));
  o[4] = bf2f((ushort)(u.z & 0xffff)); o[5] = bf2f((ushort)(u.z >> 16));
  o[6] = bf2f((ushort)(u.w & 0xffff)); o[7] = bf2f((ushort)(u.w >> 16));
}
__device__ __forceinline__ void unpack4(uint2 u, float* o) {
  o[0] = bf2f((ushort)(u.x & 0xffff)); o[1] = bf2f((ushort)(u.x >> 16));
  o[2] = bf2f((ushort)(u.y & 0xffff)); o[3] = bf2f((ushort)(u.y >> 16));
}

#define GLL16(g, l) __builtin_amdgcn_global_load_lds( \
    (__attribute__((address_space(1))) void*)(g), \
    (__attribute__((address_space(3))) void*)(l), 16, 0, 0)

// ---------------- cast fp32 -> bf16 ----------------
__global__ void cast_kernel(const float* __restrict__ src, ushort* __restrict__ dst, int n) {
  int idx = blockIdx.x * blockDim.x + threadIdx.x;
  int stride = gridDim.x * blockDim.x;
  for (int i = idx * 4; i < n; i += stride * 4) {
    float4 v = *reinterpret_cast<const float4*>(src + i);
    ushort4 o;
    o.x = f2bf(v.x); o.y = f2bf(v.y); o.z = f2bf(v.z); o.w = f2bf(v.w);
    *reinterpret_cast<ushort4*>(dst + i) = o;
  }
}

// ---------------- bf16 GEMM: C[m,n] = sum_k A[m,k]*Bw[n,k] + bias[n] ----------------
// MODE 0: bf16 out, elu+1 ; MODE 1: bf16 out ; MODE 2: f32 out
template<int MODE>
__global__ __launch_bounds__(256) void gemm_bt(
    const ushort* __restrict__ A, const ushort* __restrict__ Bw,
    const float* __restrict__ bias, void* __restrict__ Cout,
    const int K, const int N) {
  __shared__ ushort Al[128 * 32];
  __shared__ ushort Bl[128 * 32];
  const int t = threadIdx.x;
  const int lane = t & 63;
  const int w = t >> 6;
  const int m0 = blockIdx.y * 128;
  const int n0 = blockIdx.x * 128;
  const int wm = (w >> 1) * 64;
  const int wn = (w & 1) * 64;
  f32x4 acc[4][4] = {};

  const int rowA = t >> 2;
  const int kc = (t & 3) * 8;
  const size_t baseA = (size_t)(m0 + rowA) * K + kc;
  const size_t baseB = (size_t)(n0 + rowA) * K + kc;
  ushort* lA = Al + w * 512;   // wave-uniform LDS base (+lane*16B done by HW)
  ushort* lB = Bl + w * 512;

  const int fr = lane & 15;
  const int kq = (lane >> 4) * 8;
  const ushort* ra = Al + (wm + fr) * 32 + kq;
  const ushort* rb = Bl + (wn + fr) * 32 + kq;

  for (int k0 = 0; k0 < K; k0 += 32) {
    __syncthreads();
    GLL16(A + baseA + k0, lA);
    GLL16(A + baseA + (size_t)64 * K + k0, lA + 2048);
    GLL16(Bw + baseB + k0, lB);
    GLL16(Bw + baseB + (size_t)64 * K + k0, lB + 2048);
    __syncthreads();
    bf16x8 a[4], b[4];
#pragma unroll
    for (int i = 0; i < 4; ++i) {
      a[i] = *reinterpret_cast<const bf16x8*>(ra + i * 16 * 32);
      b[i] = *reinterpret_cast<const bf16x8*>(rb + i * 16 * 32);
    }
#pragma unroll
    for (int mi = 0; mi < 4; ++mi)
#pragma unroll
      for (int ni = 0; ni < 4; ++ni)
        acc[mi][ni] = __builtin_amdgcn_mfma_f32_16x16x32_bf16(a[mi], b[ni], acc[mi][ni], 0, 0, 0);
  }

  const int fq = (lane >> 4) * 4;
#pragma unroll
  for (int mi = 0; mi < 4; ++mi) {
#pragma unroll
    for (int ni = 0; ni < 4; ++ni) {
      const int c = n0 + wn + ni * 16 + fr;
      const float bv = bias[c];
#pragma unroll
      for (int q = 0; q < 4; ++q) {
        const int r = m0 + wm + mi * 16 + fq + q;
        float v = acc[mi][ni][q] + bv;
        if constexpr (MODE == 0) v = (v > 0.f) ? (v + 1.f) : __expf(v);
        if constexpr (MODE == 2) {
          reinterpret_cast<float*>(Cout)[(size_t)r * N + c] = v;
        } else {
          reinterpret_cast<ushort*>(Cout)[(size_t)r * N + c] = f2bf(v);
        }
      }
    }
  }
}

// ---------------- KV partials: per wave, KVp[slab][bh][64][64] = sum_{s in wave range} K[s,d]*V[s,e]
// grid (64 bh, 8 chunks), 256 threads = 4 waves; wave handles 128 s (2 tiles of 64).
// Per-wave-private LDS tiles staged via global_load_lds; no block barriers, no atomics.
__global__ __launch_bounds__(256) void kv_kernel(
    const ushort* __restrict__ Kp, const ushort* __restrict__ Vp,
    float* __restrict__ KVpart, float* __restrict__ Kspart) {
  __shared__ ushort KL[4][64][64];   // 32 KB
  __shared__ ushort VL[4][64][64];   // 32 KB
  const int bh = blockIdx.x;
  const int chunk = blockIdx.y;
  const int b = bh >> 4, h = bh & 15;
  const int t = threadIdx.x;
  const int w = t >> 6, lane = t & 63;
  const int d0 = (lane >> 2) * 4;      // 0..60
  const int e0 = (lane & 3) * 16;      // 0,16,32,48
  const int srow = lane >> 3;          // 0..7   (staging)
  const int scol = (lane & 7) * 8;     // 0..56  (staging, elements)

  float acc[4][16] = {};
  float ks[4] = {};

  ushort* lk = &KL[w][0][0];
  ushort* lv = &VL[w][0][0];
  const int s_wave = chunk * 512 + w * 128;

  for (int tile = 0; tile < 2; ++tile) {
    const int s0 = s_wave + tile * 64;
    const size_t gbase = (size_t)(b * SS + s0 + srow) * DM + h * 64 + scol;
    // make sure prior tile's LDS reads are done before overwriting
    asm volatile("s_waitcnt lgkmcnt(0)" ::: "memory");
#pragma unroll
    for (int it = 0; it < 8; ++it) {
      GLL16(Kp + gbase + (size_t)it * 8 * DM, lk + it * 512);
      GLL16(Vp + gbase + (size_t)it * 8 * DM, lv + it * 512);
    }
    asm volatile("s_waitcnt vmcnt(0)" ::: "memory");
    __builtin_amdgcn_sched_barrier(0);

#pragma unroll 2
    for (int s = 0; s < 64; ++s) {
      float kf[4], vf[16];
      uint2 uk = *reinterpret_cast<const uint2*>(&KL[w][s][d0]);
      uint4 uv0 = *reinterpret_cast<const uint4*>(&VL[w][s][e0]);
      uint4 uv1 = *reinterpret_cast<const uint4*>(&VL[w][s][e0 + 8]);
      unpack4(uk, kf);
      unpack8(uv0, vf);
      unpack8(uv1, vf + 8);
#pragma unroll
      for (int i = 0; i < 4; ++i) {
        ks[i] += kf[i];
#pragma unroll
        for (int j = 0; j < 16; ++j) acc[i][j] += kf[i] * vf[j];
      }
    }
  }

  // write per-wave partial: slab = chunk*4 + w
  const int slab = chunk * 4 + w;
  float* kvp = KVpart + ((size_t)slab * 64 + bh) * 4096;
#pragma unroll
  for (int i = 0; i < 4; ++i) {
#pragma unroll
    for (int j4 = 0; j4 < 4; ++j4) {
      float4 v = { acc[i][j4*4+0], acc[i][j4*4+1], acc[i][j4*4+2], acc[i][j4*4+3] };
      *reinterpret_cast<float4*>(kvp + (d0 + i) * 64 + e0 + j4 * 4) = v;
    }
  }
  // Ksum partial: the 4 lanes sharing d0 (different e0) hold IDENTICAL full
  // sums over this wave's s-range — write one copy, no reduction (R2 bug:
  // shfl-summing the 4 duplicates made Ksum 4x too large).
  if ((lane & 3) == 0) {
    float4 v = { ks[0], ks[1], ks[2], ks[3] };
    *reinterpret_cast<float4*>(Kspart + (size_t)slab * 4096 + bh * 64 + d0) = v;
  }
}

// ---------------- reduce 32 partials -> KV [64][4096], Ksum [64][64] ----------------
__global__ __launch_bounds__(256) void kvreduce_kernel(
    const float* __restrict__ KVpart, const float* __restrict__ Kspart,
    float* __restrict__ KV, float* __restrict__ Ksum) {
  const int idx = blockIdx.x * 256 + threadIdx.x;   // 0 .. 262143
  float s = 0.f;
#pragma unroll
  for (int c = 0; c < 32; ++c) s += KVpart[(size_t)c * (64 * 4096) + idx];
  KV[idx] = s;
  if (idx < 64 * 64) {
    float s2 = 0.f;
#pragma unroll
    for (int c = 0; c < 32; ++c) s2 += Kspart[(size_t)c * 4096 + idx];
    Ksum[idx] = s2;
  }
}

// ---------------- Z[s,e] = (sum_d Q[s,d]*KV[d,e]) / (sum_d Q[s,d]*Ksum[d] + 1e-6) ----------------
__global__ __launch_bounds__(256) void z_kernel(
    const ushort* __restrict__ Qp, const float* __restrict__ KV,
    const float* __restrict__ Ksum, ushort* __restrict__ Zn) {
  const int bh = blockIdx.y;
  const int b = bh >> 4, h = bh & 15;
  const int srow = blockIdx.x * 256 + threadIdx.x;
  const size_t g = (size_t)(b * SS + srow) * DM + h * 64;
  const float* __restrict__ kv = KV + (size_t)bh * 4096;
  const float* __restrict__ ksm = Ksum + bh * 64;
  float accz[64] = {};
  float accd = 0.f;
  for (int dc = 0; dc < 8; ++dc) {
    uint4 u = *reinterpret_cast<const uint4*>(Qp + g + dc * 8);
    float q[8];
    unpack8(u, q);
#pragma unroll
    for (int i = 0; i < 8; ++i) {
      const int dd = dc * 8 + i;
      accd += q[i] * ksm[dd];
      const float* row = kv + dd * 64;
#pragma unroll
      for (int e = 0; e < 64; ++e) accz[e] += q[i] * row[e];
    }
  }
  const float inv = 1.f / (accd + 1e-6f);
  ushort* o = Zn + g;
#pragma unroll
  for (int ec = 0; ec < 8; ++ec) {
    uint4 u;
    u.x = (uint32_t)f2bf(accz[ec*8+0]*inv) | ((uint32_t)f2bf(accz[ec*8+1]*inv) << 16);
    u.y = (uint32_t)f2bf(accz[ec*8+2]*inv) | ((uint32_t)f2bf(accz[ec*8+3]*inv) << 16);
    u.z = (uint32_t)f2bf(accz[ec*8+4]*inv) | ((uint32_t)f2bf(accz[ec*8+5]*inv) << 16);
    u.w = (uint32_t)f2bf(accz[ec*8+6]*inv) | ((uint32_t)f2bf(accz[ec*8+7]*inv) << 16);
    *reinterpret_cast<uint4*>(o + ec * 8) = u;
  }
}

extern "C" void kernel_launch(void* const* d_in, const int* in_sizes, int n_in,
                              void* d_out, int out_size, void* d_ws, size_t ws_size,
                              hipStream_t stream) {
  const float* query = (const float*)d_in[0];
  const float* key_  = (const float*)d_in[1];
  const float* value = (const float*)d_in[2];
  const float* w_q = (const float*)d_in[3];
  const float* b_q = (const float*)d_in[4];
  const float* w_k = (const float*)d_in[5];
  const float* b_k = (const float*)d_in[6];
  const float* w_v = (const float*)d_in[7];
  const float* b_v = (const float*)d_in[8];
  const float* w_o = (const float*)d_in[9];
  const float* b_o = (const float*)d_in[10];

  char* ws = (char*)d_ws;
  const size_t NX = (size_t)MM * DM;            // 16,777,216
  ushort* Xq = (ushort*)ws; ws += NX * 2;
  ushort* Xk = (ushort*)ws; ws += NX * 2;
  ushort* Xv = (ushort*)ws; ws += NX * 2;
  ushort* Wq = (ushort*)ws; ws += (size_t)DM * DM * 2;
  ushort* Wk = (ushort*)ws; ws += (size_t)DM * DM * 2;
  ushort* Wv = (ushort*)ws; ws += (size_t)DM * DM * 2;
  ushort* Wo = (ushort*)ws; ws += (size_t)DM * DM * 2;
  ushort* Qp = (ushort*)ws; ws += NX * 2;
  ushort* Kp = (ushort*)ws; ws += NX * 2;
  ushort* Vp = (ushort*)ws; ws += NX * 2;
  float*  KV = (float*)ws;  ws += (size_t)64 * 4096 * 4;
  float*  Ks = (float*)ws;  ws += (size_t)64 * 64 * 4;
  ushort* Zn = (ushort*)ws; ws += NX * 2;

  // KV partials alias the dead Xq/Xk buffers (inputs to projection GEMMs,
  // unused once Qp/Kp/Vp exist). KVpart: 32*64*4096*4 = 32 MiB == Xq region.
  float* KVpart = (float*)Xq;
  float* Kspart = (float*)Xk;   // 512 KiB

  cast_kernel<<<2048, 256, 0, stream>>>(query, Xq, (int)NX);
  cast_kernel<<<2048, 256, 0, stream>>>(key_,  Xk, (int)NX);
  cast_kernel<<<2048, 256, 0, stream>>>(value, Xv, (int)NX);
  cast_kernel<<<256, 256, 0, stream>>>(w_q, Wq, DM * DM);
  cast_kernel<<<256, 256, 0, stream>>>(w_k, Wk, DM * DM);
  cast_kernel<<<256, 256, 0, stream>>>(w_v, Wv, DM * DM);
  cast_kernel<<<256, 256, 0, stream>>>(w_o, Wo, DM * DM);

  dim3 gg(DM / 128, MM / 128);   // (8, 128)
  gemm_bt<0><<<gg, 256, 0, stream>>>(Xq, Wq, b_q, Qp, DM, DM);
  gemm_bt<0><<<gg, 256, 0, stream>>>(Xk, Wk, b_k, Kp, DM, DM);
  gemm_bt<1><<<gg, 256, 0, stream>>>(Xv, Wv, b_v, Vp, DM, DM);

  kv_kernel<<<dim3(64, 8), 256, 0, stream>>>(Kp, Vp, KVpart, Kspart);
  kvreduce_kernel<<<1024, 256, 0, stream>>>(KVpart, Kspart, KV, Ks);
  z_kernel<<<dim3(16, 64), 256, 0, stream>>>(Qp, KV, Ks, Zn);

  gemm_bt<2><<<gg, 256, 0, stream>>>(Zn, Wo, b_o, d_out, DM, DM);
}

// Round 4
// 391.946 us; speedup vs baseline: 1.4810x; 1.1476x over previous
//
#include <hip/hip_runtime.h>
#include <stdint.h>

#define DM 1024
#define NH 16
#define DKH 64
#define BB 4
#define SS 4096
#define MM (BB*SS)   // 16384

typedef __bf16 bf16x8 __attribute__((ext_vector_type(8)));
typedef float f32x4 __attribute__((ext_vector_type(4)));

__device__ __forceinline__ float bf2f(ushort u) {
  union { uint32_t i; float f; } v; v.i = ((uint32_t)u) << 16; return v.f;
}
__device__ __forceinline__ ushort f2bf(float f) {
  union { float f; uint32_t i; } v; v.f = f;
  uint32_t x = v.i;
  uint32_t r = (x + 0x7fffu + ((x >> 16) & 1u)) >> 16;
  return (ushort)r;
}
__device__ __forceinline__ void unpack8(uint4 u, float* o) {
  o[0] = bf2f((ushort)(u.x & 0xffff)); o[1] = bf2f((ushort)(u.x >> 16));
  o[2] = bf2f((ushort)(u.y & 0xffff)); o[3] = bf2f((ushort)(u.y >> 16));
  o[4] = bf2f((ushort)(u.z & 0xffff)); o[5] = bf2f((ushort)(u.z >> 16));
  o[6] = bf2f((ushort)(u.w & 0xffff)); o[7] = bf2f((ushort)(u.w >> 16));
}
__device__ __forceinline__ void unpack4(uint2 u, float* o) {
  o[0] = bf2f((ushort)(u.x & 0xffff)); o[1] = bf2f((ushort)(u.x >> 16));
  o[2] = bf2f((ushort)(u.y & 0xffff)); o[3] = bf2f((ushort)(u.y >> 16));
}

#define GLL16(g, l) __builtin_amdgcn_global_load_lds( \
    (__attribute__((address_space(1))) void*)(g), \
    (__attribute__((address_space(3))) void*)(l), 16, 0, 0)

// ---------------- cast fp32 -> bf16 ----------------
__global__ void cast_kernel(const float* __restrict__ src, ushort* __restrict__ dst, int n) {
  int idx = blockIdx.x * blockDim.x + threadIdx.x;
  int stride = gridDim.x * blockDim.x;
  for (int i = idx * 4; i < n; i += stride * 4) {
    float4 v = *reinterpret_cast<const float4*>(src + i);
    ushort4 o;
    o.x = f2bf(v.x); o.y = f2bf(v.y); o.z = f2bf(v.z); o.w = f2bf(v.w);
    *reinterpret_cast<ushort4*>(dst + i) = o;
  }
}

// ---------------- bf16 GEMM: C[m,n] = sum_k A[m,k]*Bw[n,k] + bias[n] ----------------
// MODE 0: bf16 out, elu+1 ; MODE 1: bf16 out ; MODE 2: f32 out
template<int MODE>
__global__ __launch_bounds__(256) void gemm_bt(
    const ushort* __restrict__ A, const ushort* __restrict__ Bw,
    const float* __restrict__ bias, void* __restrict__ Cout,
    const int K, const int N) {
  __shared__ ushort Al[128 * 32];
  __shared__ ushort Bl[128 * 32];
  const int t = threadIdx.x;
  const int lane = t & 63;
  const int w = t >> 6;
  // XCD-aware swizzle (nwg = 8*128 = 1024, divisible by 8 -> bijective):
  // consecutive ids on one XCD walk n-tiles first, sharing the A m-panel.
  const int id = blockIdx.y * gridDim.x + blockIdx.x;
  const int cpx = (gridDim.x * gridDim.y) >> 3;
  const int swz = (id & 7) * cpx + (id >> 3);
  const int bx = swz % gridDim.x;
  const int by = swz / gridDim.x;
  const int m0 = by * 128;
  const int n0 = bx * 128;
  const int wm = (w >> 1) * 64;
  const int wn = (w & 1) * 64;
  f32x4 acc[4][4] = {};

  const int rowA = t >> 2;
  const int kc = (t & 3) * 8;
  const size_t baseA = (size_t)(m0 + rowA) * K + kc;
  const size_t baseB = (size_t)(n0 + rowA) * K + kc;
  ushort* lA = Al + w * 512;   // wave-uniform LDS base (+lane*16B done by HW)
  ushort* lB = Bl + w * 512;

  const int fr = lane & 15;
  const int kq = (lane >> 4) * 8;
  const ushort* ra = Al + (wm + fr) * 32 + kq;
  const ushort* rb = Bl + (wn + fr) * 32 + kq;

  for (int k0 = 0; k0 < K; k0 += 32) {
    __syncthreads();
    GLL16(A + baseA + k0, lA);
    GLL16(A + baseA + (size_t)64 * K + k0, lA + 2048);
    GLL16(Bw + baseB + k0, lB);
    GLL16(Bw + baseB + (size_t)64 * K + k0, lB + 2048);
    __syncthreads();
    bf16x8 a[4], b[4];
#pragma unroll
    for (int i = 0; i < 4; ++i) {
      a[i] = *reinterpret_cast<const bf16x8*>(ra + i * 16 * 32);
      b[i] = *reinterpret_cast<const bf16x8*>(rb + i * 16 * 32);
    }
#pragma unroll
    for (int mi = 0; mi < 4; ++mi)
#pragma unroll
      for (int ni = 0; ni < 4; ++ni)
        acc[mi][ni] = __builtin_amdgcn_mfma_f32_16x16x32_bf16(a[mi], b[ni], acc[mi][ni], 0, 0, 0);
  }

  const int fq = (lane >> 4) * 4;
#pragma unroll
  for (int mi = 0; mi < 4; ++mi) {
#pragma unroll
    for (int ni = 0; ni < 4; ++ni) {
      const int c = n0 + wn + ni * 16 + fr;
      const float bv = bias[c];
#pragma unroll
      for (int q = 0; q < 4; ++q) {
        const int r = m0 + wm + mi * 16 + fq + q;
        float v = acc[mi][ni][q] + bv;
        if constexpr (MODE == 0) v = (v > 0.f) ? (v + 1.f) : __expf(v);
        if constexpr (MODE == 2) {
          reinterpret_cast<float*>(Cout)[(size_t)r * N + c] = v;
        } else {
          reinterpret_cast<ushort*>(Cout)[(size_t)r * N + c] = f2bf(v);
        }
      }
    }
  }
}

// ---------------- KV partials: per wave, KVp[slab][bh][64][64] = sum_{s in wave range} K[s,d]*V[s,e]
__global__ __launch_bounds__(256) void kv_kernel(
    const ushort* __restrict__ Kp, const ushort* __restrict__ Vp,
    float* __restrict__ KVpart, float* __restrict__ Kspart) {
  __shared__ ushort KL[4][64][64];   // 32 KB
  __shared__ ushort VL[4][64][64];   // 32 KB
  const int bh = blockIdx.x;
  const int chunk = blockIdx.y;
  const int b = bh >> 4, h = bh & 15;
  const int t = threadIdx.x;
  const int w = t >> 6, lane = t & 63;
  const int d0 = (lane >> 2) * 4;      // 0..60
  const int e0 = (lane & 3) * 16;      // 0,16,32,48
  const int srow = lane >> 3;          // 0..7   (staging)
  const int scol = (lane & 7) * 8;     // 0..56  (staging, elements)

  float acc[4][16] = {};
  float ks[4] = {};

  ushort* lk = &KL[w][0][0];
  ushort* lv = &VL[w][0][0];
  const int s_wave = chunk * 512 + w * 128;

  for (int tile = 0; tile < 2; ++tile) {
    const int s0 = s_wave + tile * 64;
    const size_t gbase = (size_t)(b * SS + s0 + srow) * DM + h * 64 + scol;
    asm volatile("s_waitcnt lgkmcnt(0)" ::: "memory");
#pragma unroll
    for (int it = 0; it < 8; ++it) {
      GLL16(Kp + gbase + (size_t)it * 8 * DM, lk + it * 512);
      GLL16(Vp + gbase + (size_t)it * 8 * DM, lv + it * 512);
    }
    asm volatile("s_waitcnt vmcnt(0)" ::: "memory");
    __builtin_amdgcn_sched_barrier(0);

#pragma unroll 2
    for (int s = 0; s < 64; ++s) {
      float kf[4], vf[16];
      uint2 uk = *reinterpret_cast<const uint2*>(&KL[w][s][d0]);
      uint4 uv0 = *reinterpret_cast<const uint4*>(&VL[w][s][e0]);
      uint4 uv1 = *reinterpret_cast<const uint4*>(&VL[w][s][e0 + 8]);
      unpack4(uk, kf);
      unpack8(uv0, vf);
      unpack8(uv1, vf + 8);
#pragma unroll
      for (int i = 0; i < 4; ++i) {
        ks[i] += kf[i];
#pragma unroll
        for (int j = 0; j < 16; ++j) acc[i][j] += kf[i] * vf[j];
      }
    }
  }

  const int slab = chunk * 4 + w;
  float* kvp = KVpart + ((size_t)slab * 64 + bh) * 4096;
#pragma unroll
  for (int i = 0; i < 4; ++i) {
#pragma unroll
    for (int j4 = 0; j4 < 4; ++j4) {
      float4 v = { acc[i][j4*4+0], acc[i][j4*4+1], acc[i][j4*4+2], acc[i][j4*4+3] };
      *reinterpret_cast<float4*>(kvp + (d0 + i) * 64 + e0 + j4 * 4) = v;
    }
  }
  // 4 lanes sharing d0 hold IDENTICAL sums — write one copy, no reduction.
  if ((lane & 3) == 0) {
    float4 v = { ks[0], ks[1], ks[2], ks[3] };
    *reinterpret_cast<float4*>(Kspart + (size_t)slab * 4096 + bh * 64 + d0) = v;
  }
}

// ---------------- reduce 32 partials -> KVTx bf16 [bh][80][64]:
// rows 0..63 = KV^T (row e, col d), row 64 = Ksum, rows 65..79 = 0 (pre-memset).
__global__ __launch_bounds__(256) void kvreduce_kernel(
    const float* __restrict__ KVpart, const float* __restrict__ Kspart,
    ushort* __restrict__ KVTx) {
  const int idx = blockIdx.x * 256 + threadIdx.x;   // 0 .. 262143
  const int bh = idx >> 12;
  const int d = (idx >> 6) & 63;
  const int e = idx & 63;
  float s = 0.f;
#pragma unroll
  for (int c = 0; c < 32; ++c) s += KVpart[(size_t)c * (64 * 4096) + idx];
  KVTx[(size_t)bh * 5120 + e * 64 + d] = f2bf(s);
  if (idx < 64 * 64) {
    float s2 = 0.f;
#pragma unroll
    for (int c = 0; c < 32; ++c) s2 += Kspart[(size_t)c * 4096 + idx];
    KVTx[(size_t)(idx >> 6) * 5120 + 4096 + (idx & 63)] = f2bf(s2);
  }
}

// ---------------- Z via MFMA: per (bh, 128-row tile). 4 waves x 32 rows.
// B = KVTx[bh] (80 rows: e=0..63 -> Z cols, row 64 = Ksum -> denominator col).
__global__ __launch_bounds__(256) void z_mfma_kernel(
    const ushort* __restrict__ Qp, const ushort* __restrict__ KVTx,
    ushort* __restrict__ Zn) {
  const int bh = blockIdx.y;
  const int b = bh >> 4, h = bh & 15;
  const int t = threadIdx.x;
  const int w = t >> 6, lane = t & 63;
  const int fr = lane & 15;
  const int kq = (lane >> 4) * 8;          // 0,8,16,24 (elements)
  const int s0 = blockIdx.x * 128 + w * 32;

  const ushort* kvb = KVTx + (size_t)bh * 5120;
  bf16x8 bfrag[5][2];
#pragma unroll
  for (int ni = 0; ni < 5; ++ni)
#pragma unroll
    for (int ks = 0; ks < 2; ++ks)
      bfrag[ni][ks] = *reinterpret_cast<const bf16x8*>(kvb + (ni * 16 + fr) * 64 + ks * 32 + kq);

  f32x4 acc[2][5] = {};
  const size_t arow = (size_t)(b * SS + s0 + fr) * DM + h * 64;
#pragma unroll
  for (int mi = 0; mi < 2; ++mi) {
#pragma unroll
    for (int ks = 0; ks < 2; ++ks) {
      bf16x8 a = *reinterpret_cast<const bf16x8*>(Qp + arow + (size_t)mi * 16 * DM + ks * 32 + kq);
#pragma unroll
      for (int ni = 0; ni < 5; ++ni)
        acc[mi][ni] = __builtin_amdgcn_mfma_f32_16x16x32_bf16(a, bfrag[ni][ks], acc[mi][ni], 0, 0, 0);
    }
  }

  // epilogue: col 64 (fr==0 lane of ni=4 fragment) holds D; broadcast within row group.
#pragma unroll
  for (int mi = 0; mi < 2; ++mi) {
#pragma unroll
    for (int q = 0; q < 4; ++q) {
      const float dv = __shfl(acc[mi][4][q], lane & 48);
      const float inv = 1.f / (dv + 1e-6f);
      const int r = s0 + mi * 16 + (lane >> 4) * 4 + q;
      ushort* orow = Zn + (size_t)(b * SS + r) * DM + h * 64;
#pragma unroll
      for (int ni = 0; ni < 4; ++ni)
        orow[ni * 16 + fr] = f2bf(acc[mi][ni][q] * inv);
    }
  }
}

extern "C" void kernel_launch(void* const* d_in, const int* in_sizes, int n_in,
                              void* d_out, int out_size, void* d_ws, size_t ws_size,
                              hipStream_t stream) {
  const float* query = (const float*)d_in[0];
  const float* key_  = (const float*)d_in[1];
  const float* value = (const float*)d_in[2];
  const float* w_q = (const float*)d_in[3];
  const float* b_q = (const float*)d_in[4];
  const float* w_k = (const float*)d_in[5];
  const float* b_k = (const float*)d_in[6];
  const float* w_v = (const float*)d_in[7];
  const float* b_v = (const float*)d_in[8];
  const float* w_o = (const float*)d_in[9];
  const float* b_o = (const float*)d_in[10];

  char* ws = (char*)d_ws;
  const size_t NX = (size_t)MM * DM;            // 16,777,216
  ushort* Xq = (ushort*)ws; ws += NX * 2;
  ushort* Xk = (ushort*)ws; ws += NX * 2;
  ushort* Xv = (ushort*)ws; ws += NX * 2;
  ushort* Wq = (ushort*)ws; ws += (size_t)DM * DM * 2;
  ushort* Wk = (ushort*)ws; ws += (size_t)DM * DM * 2;
  ushort* Wv = (ushort*)ws; ws += (size_t)DM * DM * 2;
  ushort* Wo = (ushort*)ws; ws += (size_t)DM * DM * 2;
  ushort* Qp = (ushort*)ws; ws += NX * 2;
  ushort* Kp = (ushort*)ws; ws += NX * 2;
  ushort* Vp = (ushort*)ws; ws += NX * 2;
  ushort* KVTx = (ushort*)ws; ws += (size_t)64 * 80 * 64 * 2;   // 640 KiB
  ushort* Zn = (ushort*)ws; ws += NX * 2;

  // KV partials alias the dead Xq/Xk buffers (unused once Qp/Kp/Vp exist).
  float* KVpart = (float*)Xq;   // 32 MiB
  float* Kspart = (float*)Xk;   // 512 KiB

  cast_kernel<<<2048, 256, 0, stream>>>(query, Xq, (int)NX);
  cast_kernel<<<2048, 256, 0, stream>>>(key_,  Xk, (int)NX);
  cast_kernel<<<2048, 256, 0, stream>>>(value, Xv, (int)NX);
  cast_kernel<<<256, 256, 0, stream>>>(w_q, Wq, DM * DM);
  cast_kernel<<<256, 256, 0, stream>>>(w_k, Wk, DM * DM);
  cast_kernel<<<256, 256, 0, stream>>>(w_v, Wv, DM * DM);
  cast_kernel<<<256, 256, 0, stream>>>(w_o, Wo, DM * DM);

  dim3 gg(DM / 128, MM / 128);   // (8, 128)
  gemm_bt<0><<<gg, 256, 0, stream>>>(Xq, Wq, b_q, Qp, DM, DM);
  gemm_bt<0><<<gg, 256, 0, stream>>>(Xk, Wk, b_k, Kp, DM, DM);
  gemm_bt<1><<<gg, 256, 0, stream>>>(Xv, Wv, b_v, Vp, DM, DM);

  kv_kernel<<<dim3(64, 8), 256, 0, stream>>>(Kp, Vp, KVpart, Kspart);
  hipMemsetAsync(KVTx, 0, (size_t)64 * 80 * 64 * 2, stream);   // zero rows 65..79
  kvreduce_kernel<<<1024, 256, 0, stream>>>(KVpart, Kspart, KVTx);
  z_mfma_kernel<<<dim3(32, 64), 256, 0, stream>>>(Qp, KVTx, Zn);

  gemm_bt<2><<<gg, 256, 0, stream>>>(Zn, Wo, b_o, d_out, DM, DM);
}

// Round 5
// 348.564 us; speedup vs baseline: 1.6653x; 1.1245x over previous
//
#include <hip/hip_runtime.h>
#include <stdint.h>

#define DM 1024
#define NH 16
#define DKH 64
#define BB 4
#define SS 4096
#define MM (BB*SS)   // 16384

typedef __bf16 bf16x8 __attribute__((ext_vector_type(8)));
typedef float f32x4 __attribute__((ext_vector_type(4)));

__device__ __forceinline__ float bf2f(ushort u) {
  union { uint32_t i; float f; } v; v.i = ((uint32_t)u) << 16; return v.f;
}
__device__ __forceinline__ ushort f2bf(float f) {
  union { float f; uint32_t i; } v; v.f = f;
  uint32_t x = v.i;
  uint32_t r = (x + 0x7fffu + ((x >> 16) & 1u)) >> 16;
  return (ushort)r;
}
__device__ __forceinline__ void unpack8(uint4 u, float* o) {
  o[0] = bf2f((ushort)(u.x & 0xffff)); o[1] = bf2f((ushort)(u.x >> 16));
  o[2] = bf2f((ushort)(u.y & 0xffff)); o[3] = bf2f((ushort)(u.y >> 16));
  o[4] = bf2f((ushort)(u.z & 0xffff)); o[5] = bf2f((ushort)(u.z >> 16));
  o[6] = bf2f((ushort)(u.w & 0xffff)); o[7] = bf2f((ushort)(u.w >> 16));
}
__device__ __forceinline__ void unpack4(uint2 u, float* o) {
  o[0] = bf2f((ushort)(u.x & 0xffff)); o[1] = bf2f((ushort)(u.x >> 16));
  o[2] = bf2f((ushort)(u.y & 0xffff)); o[3] = bf2f((ushort)(u.y >> 16));
}

#define GLL16(g, l) __builtin_amdgcn_global_load_lds( \
    (__attribute__((address_space(1))) void*)(g), \
    (__attribute__((address_space(3))) void*)(l), 16, 0, 0)

// ---------------- fused cast fp32 -> bf16: 3 big inputs in one launch ----------------
__global__ void cast_in3(const float* __restrict__ s0, const float* __restrict__ s1,
                         const float* __restrict__ s2, ushort* __restrict__ d0,
                         ushort* __restrict__ d1, ushort* __restrict__ d2) {
  const int which = blockIdx.x >> 14;              // 16384 blocks per tensor
  const int i = ((blockIdx.x & 16383) * 256 + threadIdx.x) * 4;
  const float* src = which == 0 ? s0 : (which == 1 ? s1 : s2);
  ushort* dst = which == 0 ? d0 : (which == 1 ? d1 : d2);
  float4 v = *reinterpret_cast<const float4*>(src + i);
  ushort4 o; o.x = f2bf(v.x); o.y = f2bf(v.y); o.z = f2bf(v.z); o.w = f2bf(v.w);
  *reinterpret_cast<ushort4*>(dst + i) = o;
}
// ---------------- fused cast: 4 weight matrices in one launch ----------------
__global__ void cast_w4(const float* __restrict__ s0, const float* __restrict__ s1,
                        const float* __restrict__ s2, const float* __restrict__ s3,
                        ushort* __restrict__ d0, ushort* __restrict__ d1,
                        ushort* __restrict__ d2, ushort* __restrict__ d3) {
  const int which = blockIdx.x >> 10;              // 1024 blocks per tensor
  const int i = ((blockIdx.x & 1023) * 256 + threadIdx.x) * 4;
  const float* src = which == 0 ? s0 : (which == 1 ? s1 : (which == 2 ? s2 : s3));
  ushort* dst = which == 0 ? d0 : (which == 1 ? d1 : (which == 2 ? d2 : d3));
  float4 v = *reinterpret_cast<const float4*>(src + i);
  ushort4 o; o.x = f2bf(v.x); o.y = f2bf(v.y); o.z = f2bf(v.z); o.w = f2bf(v.w);
  *reinterpret_cast<ushort4*>(dst + i) = o;
}

// ---------------- 256x256 2-phase bf16 GEMM: C[m,n] = sum_k A[m,k]*Bw[n,k] + bias[n]
// 512 threads = 8 waves (2M x 4N), BK=64, double-buffered 128 KiB LDS,
// stage(next) issued BEFORE compute(cur), ONE __syncthreads per K-step (T3 min-2-phase).
// MODE 0: bf16 out + elu+1 ; MODE 1: bf16 out ; MODE 2: f32 out
template<int MODE>
__global__ __launch_bounds__(512, 2) void gemm256(
    const ushort* __restrict__ A, const ushort* __restrict__ Bw,
    const float* __restrict__ bias, void* __restrict__ Cout,
    const int K, const int N) {
  __shared__ ushort Abuf[2][256 * 64];   // 64 KiB
  __shared__ ushort Bbuf[2][256 * 64];   // 64 KiB
  const int t = threadIdx.x;
  const int lane = t & 63;
  const int w = t >> 6;
  // XCD-aware swizzle (nwg = 256, %8 == 0 -> bijective)
  const int id = blockIdx.y * gridDim.x + blockIdx.x;
  const int cpx = (gridDim.x * gridDim.y) >> 3;
  const int swz = (id & 7) * cpx + (id >> 3);
  const int bx = swz % gridDim.x;
  const int by = swz / gridDim.x;
  const int m0 = by * 256, n0 = bx * 256;
  const int wm = w >> 2, wn = w & 3;              // wave tile: 128 x 64
  const int fr = lane & 15, kq = (lane >> 4) * 8;

  // staging: thread t loads 16B at row (t>>3)+l*64, col (t&7)*8, l=0..3 (A and B)
  const size_t gA = (size_t)(m0 + (t >> 3)) * K + (t & 7) * 8;
  const size_t gB = (size_t)(n0 + (t >> 3)) * K + (t & 7) * 8;
  const int ldsbase = w * 512;                    // elements; lane*16B added by HW

  f32x4 acc[8][4] = {};
  const int arow = wm * 128 + fr;
  const int brow = wn * 64 + fr;

  const int NT = K >> 6;   // 16
  int cur = 0;

  // prologue: stage tile 0
#pragma unroll
  for (int l = 0; l < 4; ++l) {
    GLL16(A + gA + (size_t)l * 64 * K, &Abuf[0][ldsbase + l * 4096]);
    GLL16(Bw + gB + (size_t)l * 64 * K, &Bbuf[0][ldsbase + l * 4096]);
  }
  __syncthreads();

  for (int kt = 0; kt < NT - 1; ++kt) {
    // phase 1: issue next tile's stage (overlaps with compute below)
    const size_t k0 = (size_t)(kt + 1) * 64;
#pragma unroll
    for (int l = 0; l < 4; ++l) {
      GLL16(A + gA + (size_t)l * 64 * K + k0, &Abuf[cur ^ 1][ldsbase + l * 4096]);
      GLL16(Bw + gB + (size_t)l * 64 * K + k0, &Bbuf[cur ^ 1][ldsbase + l * 4096]);
    }
    // phase 2: compute current tile
#pragma unroll
    for (int ks = 0; ks < 2; ++ks) {
      bf16x8 a[8], b[4];
#pragma unroll
      for (int mi = 0; mi < 8; ++mi)
        a[mi] = *reinterpret_cast<const bf16x8*>(&Abuf[cur][(arow + mi * 16) * 64 + ks * 32 + kq]);
#pragma unroll
      for (int ni = 0; ni < 4; ++ni)
        b[ni] = *reinterpret_cast<const bf16x8*>(&Bbuf[cur][(brow + ni * 16) * 64 + ks * 32 + kq]);
#pragma unroll
      for (int mi = 0; mi < 8; ++mi)
#pragma unroll
        for (int ni = 0; ni < 4; ++ni)
          acc[mi][ni] = __builtin_amdgcn_mfma_f32_16x16x32_bf16(a[mi], b[ni], acc[mi][ni], 0, 0, 0);
    }
    __syncthreads();   // vmcnt(0)+lgkmcnt(0)+barrier: next tile resident, cur consumed
    cur ^= 1;
  }
  // epilogue K-step (no prefetch)
#pragma unroll
  for (int ks = 0; ks < 2; ++ks) {
    bf16x8 a[8], b[4];
#pragma unroll
    for (int mi = 0; mi < 8; ++mi)
      a[mi] = *reinterpret_cast<const bf16x8*>(&Abuf[cur][(arow + mi * 16) * 64 + ks * 32 + kq]);
#pragma unroll
    for (int ni = 0; ni < 4; ++ni)
      b[ni] = *reinterpret_cast<const bf16x8*>(&Bbuf[cur][(brow + ni * 16) * 64 + ks * 32 + kq]);
#pragma unroll
    for (int mi = 0; mi < 8; ++mi)
#pragma unroll
      for (int ni = 0; ni < 4; ++ni)
        acc[mi][ni] = __builtin_amdgcn_mfma_f32_16x16x32_bf16(a[mi], b[ni], acc[mi][ni], 0, 0, 0);
  }

  // epilogue: bias (+elu) + store
  const int fq = (lane >> 4) * 4;
  float bv[4];
#pragma unroll
  for (int ni = 0; ni < 4; ++ni) bv[ni] = bias[n0 + wn * 64 + ni * 16 + fr];
#pragma unroll
  for (int mi = 0; mi < 8; ++mi) {
#pragma unroll
    for (int ni = 0; ni < 4; ++ni) {
      const int c = n0 + wn * 64 + ni * 16 + fr;
#pragma unroll
      for (int q = 0; q < 4; ++q) {
        const int r = m0 + wm * 128 + mi * 16 + fq + q;
        float v = acc[mi][ni][q] + bv[ni];
        if constexpr (MODE == 0) v = (v > 0.f) ? (v + 1.f) : __expf(v);
        if constexpr (MODE == 2) {
          reinterpret_cast<float*>(Cout)[(size_t)r * N + c] = v;
        } else {
          reinterpret_cast<ushort*>(Cout)[(size_t)r * N + c] = f2bf(v);
        }
      }
    }
  }
}

// ---------------- KV partials: per wave, KVp[slab][bh][64][64] = sum_{s in range} K[s,d]*V[s,e]
__global__ __launch_bounds__(256) void kv_kernel(
    const ushort* __restrict__ Kp, const ushort* __restrict__ Vp,
    float* __restrict__ KVpart, float* __restrict__ Kspart) {
  __shared__ ushort KL[4][64][64];
  __shared__ ushort VL[4][64][64];
  const int bh = blockIdx.x;
  const int chunk = blockIdx.y;
  const int b = bh >> 4, h = bh & 15;
  const int t = threadIdx.x;
  const int w = t >> 6, lane = t & 63;
  const int d0 = (lane >> 2) * 4;
  const int e0 = (lane & 3) * 16;
  const int srow = lane >> 3;
  const int scol = (lane & 7) * 8;

  float acc[4][16] = {};
  float ks[4] = {};

  ushort* lk = &KL[w][0][0];
  ushort* lv = &VL[w][0][0];
  const int s_wave = chunk * 512 + w * 128;

  for (int tile = 0; tile < 2; ++tile) {
    const int s0 = s_wave + tile * 64;
    const size_t gbase = (size_t)(b * SS + s0 + srow) * DM + h * 64 + scol;
    asm volatile("s_waitcnt lgkmcnt(0)" ::: "memory");
#pragma unroll
    for (int it = 0; it < 8; ++it) {
      GLL16(Kp + gbase + (size_t)it * 8 * DM, lk + it * 512);
      GLL16(Vp + gbase + (size_t)it * 8 * DM, lv + it * 512);
    }
    asm volatile("s_waitcnt vmcnt(0)" ::: "memory");
    __builtin_amdgcn_sched_barrier(0);

#pragma unroll 2
    for (int s = 0; s < 64; ++s) {
      float kf[4], vf[16];
      uint2 uk = *reinterpret_cast<const uint2*>(&KL[w][s][d0]);
      uint4 uv0 = *reinterpret_cast<const uint4*>(&VL[w][s][e0]);
      uint4 uv1 = *reinterpret_cast<const uint4*>(&VL[w][s][e0 + 8]);
      unpack4(uk, kf);
      unpack8(uv0, vf);
      unpack8(uv1, vf + 8);
#pragma unroll
      for (int i = 0; i < 4; ++i) {
        ks[i] += kf[i];
#pragma unroll
        for (int j = 0; j < 16; ++j) acc[i][j] += kf[i] * vf[j];
      }
    }
  }

  const int slab = chunk * 4 + w;
  float* kvp = KVpart + ((size_t)slab * 64 + bh) * 4096;
#pragma unroll
  for (int i = 0; i < 4; ++i) {
#pragma unroll
    for (int j4 = 0; j4 < 4; ++j4) {
      float4 v = { acc[i][j4*4+0], acc[i][j4*4+1], acc[i][j4*4+2], acc[i][j4*4+3] };
      *reinterpret_cast<float4*>(kvp + (d0 + i) * 64 + e0 + j4 * 4) = v;
    }
  }
  // 4 lanes sharing d0 hold IDENTICAL sums — write one copy, no reduction.
  if ((lane & 3) == 0) {
    float4 v = { ks[0], ks[1], ks[2], ks[3] };
    *reinterpret_cast<float4*>(Kspart + (size_t)slab * 4096 + bh * 64 + d0) = v;
  }
}

// ---------------- reduce 32 partials -> KVTx bf16 [bh][80][64]:
// rows 0..63 = KV^T (row e, col d), row 64 = Ksum, rows 65..79 = 0 (pre-memset).
__global__ __launch_bounds__(256) void kvreduce_kernel(
    const float* __restrict__ KVpart, const float* __restrict__ Kspart,
    ushort* __restrict__ KVTx) {
  const int idx = blockIdx.x * 256 + threadIdx.x;
  const int bh = idx >> 12;
  const int d = (idx >> 6) & 63;
  const int e = idx & 63;
  float s = 0.f;
#pragma unroll
  for (int c = 0; c < 32; ++c) s += KVpart[(size_t)c * (64 * 4096) + idx];
  KVTx[(size_t)bh * 5120 + e * 64 + d] = f2bf(s);
  if (idx < 64 * 64) {
    float s2 = 0.f;
#pragma unroll
    for (int c = 0; c < 32; ++c) s2 += Kspart[(size_t)c * 4096 + idx];
    KVTx[(size_t)(idx >> 6) * 5120 + 4096 + (idx & 63)] = f2bf(s2);
  }
}

// ---------------- Z via MFMA: per (bh, 128-row tile). 4 waves x 32 rows.
__global__ __launch_bounds__(256) void z_mfma_kernel(
    const ushort* __restrict__ Qp, const ushort* __restrict__ KVTx,
    ushort* __restrict__ Zn) {
  const int bh = blockIdx.y;
  const int b = bh >> 4, h = bh & 15;
  const int t = threadIdx.x;
  const int w = t >> 6, lane = t & 63;
  const int fr = lane & 15;
  const int kq = (lane >> 4) * 8;
  const int s0 = blockIdx.x * 128 + w * 32;

  const ushort* kvb = KVTx + (size_t)bh * 5120;
  bf16x8 bfrag[5][2];
#pragma unroll
  for (int ni = 0; ni < 5; ++ni)
#pragma unroll
    for (int ks = 0; ks < 2; ++ks)
      bfrag[ni][ks] = *reinterpret_cast<const bf16x8*>(kvb + (ni * 16 + fr) * 64 + ks * 32 + kq);

  f32x4 acc[2][5] = {};
  const size_t arow = (size_t)(b * SS + s0 + fr) * DM + h * 64;
#pragma unroll
  for (int mi = 0; mi < 2; ++mi) {
#pragma unroll
    for (int ks = 0; ks < 2; ++ks) {
      bf16x8 a = *reinterpret_cast<const bf16x8*>(Qp + arow + (size_t)mi * 16 * DM + ks * 32 + kq);
#pragma unroll
      for (int ni = 0; ni < 5; ++ni)
        acc[mi][ni] = __builtin_amdgcn_mfma_f32_16x16x32_bf16(a, bfrag[ni][ks], acc[mi][ni], 0, 0, 0);
    }
  }

#pragma unroll
  for (int mi = 0; mi < 2; ++mi) {
#pragma unroll
    for (int q = 0; q < 4; ++q) {
      const float dv = __shfl(acc[mi][4][q], lane & 48);
      const float inv = 1.f / (dv + 1e-6f);
      const int r = s0 + mi * 16 + (lane >> 4) * 4 + q;
      ushort* orow = Zn + (size_t)(b * SS + r) * DM + h * 64;
#pragma unroll
      for (int ni = 0; ni < 4; ++ni)
        orow[ni * 16 + fr] = f2bf(acc[mi][ni][q] * inv);
    }
  }
}

extern "C" void kernel_launch(void* const* d_in, const int* in_sizes, int n_in,
                              void* d_out, int out_size, void* d_ws, size_t ws_size,
                              hipStream_t stream) {
  const float* query = (const float*)d_in[0];
  const float* key_  = (const float*)d_in[1];
  const float* value = (const float*)d_in[2];
  const float* w_q = (const float*)d_in[3];
  const float* b_q = (const float*)d_in[4];
  const float* w_k = (const float*)d_in[5];
  const float* b_k = (const float*)d_in[6];
  const float* w_v = (const float*)d_in[7];
  const float* b_v = (const float*)d_in[8];
  const float* w_o = (const float*)d_in[9];
  const float* b_o = (const float*)d_in[10];

  char* ws = (char*)d_ws;
  const size_t NX = (size_t)MM * DM;            // 16,777,216
  ushort* Xq = (ushort*)ws; ws += NX * 2;
  ushort* Xk = (ushort*)ws; ws += NX * 2;
  ushort* Xv = (ushort*)ws; ws += NX * 2;
  ushort* Wq = (ushort*)ws; ws += (size_t)DM * DM * 2;
  ushort* Wk = (ushort*)ws; ws += (size_t)DM * DM * 2;
  ushort* Wv = (ushort*)ws; ws += (size_t)DM * DM * 2;
  ushort* Wo = (ushort*)ws; ws += (size_t)DM * DM * 2;
  ushort* Qp = (ushort*)ws; ws += NX * 2;
  ushort* Kp = (ushort*)ws; ws += NX * 2;
  ushort* Vp = (ushort*)ws; ws += NX * 2;
  ushort* KVTx = (ushort*)ws; ws += (size_t)64 * 80 * 64 * 2;   // 640 KiB
  ushort* Zn = (ushort*)ws; ws += NX * 2;

  // KV partials alias the dead Xq/Xk buffers (unused once Qp/Kp/Vp exist).
  float* KVpart = (float*)Xq;   // 32 MiB
  float* Kspart = (float*)Xk;   // 512 KiB

  cast_in3<<<3 * 16384, 256, 0, stream>>>(query, key_, value, Xq, Xk, Xv);
  cast_w4<<<4 * 1024, 256, 0, stream>>>(w_q, w_k, w_v, w_o, Wq, Wk, Wv, Wo);

  dim3 gg(DM / 256, MM / 256);   // (4, 64)
  gemm256<0><<<gg, 512, 0, stream>>>(Xq, Wq, b_q, Qp, DM, DM);
  gemm256<0><<<gg, 512, 0, stream>>>(Xk, Wk, b_k, Kp, DM, DM);
  gemm256<1><<<gg, 512, 0, stream>>>(Xv, Wv, b_v, Vp, DM, DM);

  kv_kernel<<<dim3(64, 8), 256, 0, stream>>>(Kp, Vp, KVpart, Kspart);
  hipMemsetAsync(KVTx, 0, (size_t)64 * 80 * 64 * 2, stream);   // zero rows 65..79
  kvreduce_kernel<<<1024, 256, 0, stream>>>(KVpart, Kspart, KVTx);
  z_mfma_kernel<<<dim3(32, 64), 256, 0, stream>>>(Qp, KVTx, Zn);

  gemm256<2><<<gg, 512, 0, stream>>>(Zn, Wo, b_o, d_out, DM, DM);
}